// Round 10
// baseline (258.487 us; speedup 1.0000x reference)
//
#include <hip/hip_runtime.h>
#include <hip/hip_bf16.h>

// B=2048, T=128, H=48, L=3. Gates G=192.
// WG = 3 waves (192 thr) x 4 batches; 512 WGs. R9 lesson: launch_bounds(192,2)
// clamped VGPR to 128 -> scratch spill (FETCH 23.7MB, WRITE 46.5MB, 350GB/s).
// Fix: launch_bounds(192,1); allocator lands ~220-244 <= 256 (R8 evidence),
// which still permits 2 waves/SIMD -> 2 WGs/CU co-resident (R9 occupancy
// counter proves the scheduler does this when VGPRs fit).
// Weights in registers. 3 barriers/step. 1 cell/lane: lane (c,kg,wv) owns
// cell (j=16wv+c, b=kg); M=16 rows duplicate 4 batches 4x so acc elem r =
// batch r in EVERY lane -> gate extraction = sel4 cndmask tree, scalar cell.
//
// Mapping (validated R1-R8): A-frag lane(c,kg) = A[m=c][k=8kg..+7] per
// 32-wide ktile; B-frag = W[n][k0..+7], n = 48g+16wv+c; D elem r of lane
// (c,kg) = D[m=4kg+r][n=c], batch = m&3 = r.

using bf16x8 = __attribute__((ext_vector_type(8))) __bf16;
using u16x8  = __attribute__((ext_vector_type(8))) unsigned short;
using f32x4  = __attribute__((ext_vector_type(4))) float;

__device__ __forceinline__ float fexp2(float x){ return __builtin_amdgcn_exp2f(x); }
__device__ __forceinline__ float frcp (float x){ return __builtin_amdgcn_rcpf(x); }
__device__ __forceinline__ float sigm (float x){ return frcp(1.f + fexp2(-1.44269504f*x)); }
__device__ __forceinline__ float tanha(float x){ return 1.f - 2.f*frcp(1.f + fexp2(2.88539008f*x)); }

__device__ __forceinline__ unsigned short f2bf(float x){
  unsigned u = __float_as_uint(x);
  return (unsigned short)((u + 0x7FFFu + ((u>>16)&1u)) >> 16);  // RNE
}

__device__ __forceinline__ f32x4 mfma16(u16x8 a, u16x8 b, f32x4 c){
  return __builtin_amdgcn_mfma_f32_16x16x32_bf16(
      __builtin_bit_cast(bf16x8, a), __builtin_bit_cast(bf16x8, b), c, 0, 0, 0);
}

// element kg of a f32x4 acc, via cndmask tree (kg lane-varying, no scratch)
__device__ __forceinline__ float sel4(const f32x4& a, int kg){
  const float e01 = (kg & 1) ? a[1] : a[0];
  const float e23 = (kg & 1) ? a[3] : a[2];
  return (kg & 2) ? e23 : e01;
}

#define MM4(A, WK) \
  ac0 = mfma16(A, WK[0], ac0); ac1 = mfma16(A, WK[1], ac1); \
  ac2 = mfma16(A, WK[2], ac2); ac3 = mfma16(A, WK[3], ac3);

__global__ __launch_bounds__(192, 1) void lstm_fused(
    const float* __restrict__ adj, const float* __restrict__ eps,
    const float* __restrict__ Wi,  const float* __restrict__ bi,
    const float* __restrict__ Wa,  const float* __restrict__ ba,
    const float* __restrict__ Wp,  const float* __restrict__ bp,
    const float* __restrict__ Wih, const float* __restrict__ Whh,
    const float* __restrict__ bih, const float* __restrict__ bhh,
    const float* __restrict__ h0,  const float* __restrict__ c0,
    float* __restrict__ out)
{
  const int tid  = threadIdx.x;
  const int wv   = tid >> 6;          // 0..2
  const int lane = tid & 63;
  const int c    = lane & 15;
  const int kg   = lane >> 4;         // 0..3; owned batch = kg
  const int j    = 16*wv + c;         // owned hidden index
  const int b0   = blockIdx.x * 4;    // 4 batches per WG
  const int cr   = c & 3;             // A-row batch for frag reads

  __shared__ __align__(16) unsigned short hbuf[3][4][104]; // h_l; [48..63] = 0 pad
  __shared__ __align__(16) float adjT[128][4];
  __shared__ __align__(16) float epsT[128][4];
  __shared__ __align__(16) float outb[128][4];

  // ---- weight fragments -> registers ----
  u16x8 wf1[3][4], wf2[3][4];  // layers 1,2: [Wih|Whh], K=96
  u16x8 wf0[2][4], wfx[2][4];  // layer 0: Whh (K=48 pad 64); Wih (u/v passes)
  u16x8 wpf[2];                // Wp replicated across all 16 columns
  float biasr0[4], biasr1[4], biasr2[4];
#pragma unroll
  for (int kk = 0; kk < 3; ++kk) {
    const int k0 = 32*kk + 8*kg;
#pragma unroll
    for (int g = 0; g < 4; ++g) {
      const int n = 48*g + j;
#pragma unroll
      for (int l = 1; l < 3; ++l) {
        const float* src = (k0 < 48) ? (Wih + ((l*192 + n)*48 + k0))
                                     : (Whh + ((l*192 + n)*48 + (k0 - 48)));
        float4 p0 = *reinterpret_cast<const float4*>(src);
        float4 p1 = *reinterpret_cast<const float4*>(src + 4);
        u16x8 f;
        f[0]=f2bf(p0.x); f[1]=f2bf(p0.y); f[2]=f2bf(p0.z); f[3]=f2bf(p0.w);
        f[4]=f2bf(p1.x); f[5]=f2bf(p1.y); f[6]=f2bf(p1.z); f[7]=f2bf(p1.w);
        if (l == 1) wf1[kk][g] = f; else wf2[kk][g] = f;
      }
    }
  }
#pragma unroll
  for (int kk = 0; kk < 2; ++kk) {
    const int k0 = 32*kk + 8*kg;
#pragma unroll
    for (int g = 0; g < 4; ++g) {
      const int n = 48*g + j;
      u16x8 fh = {0,0,0,0,0,0,0,0}, fx = fh;
      if (k0 < 48) {
        const float* sh = Whh + (n*48 + k0);      // layer 0
        const float* sx = Wih + (n*48 + k0);
        float4 p0 = *reinterpret_cast<const float4*>(sh);
        float4 p1 = *reinterpret_cast<const float4*>(sh + 4);
        fh[0]=f2bf(p0.x); fh[1]=f2bf(p0.y); fh[2]=f2bf(p0.z); fh[3]=f2bf(p0.w);
        fh[4]=f2bf(p1.x); fh[5]=f2bf(p1.y); fh[6]=f2bf(p1.z); fh[7]=f2bf(p1.w);
        p0 = *reinterpret_cast<const float4*>(sx);
        p1 = *reinterpret_cast<const float4*>(sx + 4);
        fx[0]=f2bf(p0.x); fx[1]=f2bf(p0.y); fx[2]=f2bf(p0.z); fx[3]=f2bf(p0.w);
        fx[4]=f2bf(p1.x); fx[5]=f2bf(p1.y); fx[6]=f2bf(p1.z); fx[7]=f2bf(p1.w);
      }
      wf0[kk][g] = fh; wfx[kk][g] = fx;
    }
    u16x8 fp = {0,0,0,0,0,0,0,0};
#pragma unroll
    for (int e = 0; e < 8; ++e) {
      const int k = k0 + e;
      if (k < 48) fp[e] = f2bf(Wp[k]);
    }
    wpf[kk] = fp;
  }
#pragma unroll
  for (int g = 0; g < 4; ++g) {
    const int n = 48*g + j;
    biasr0[g] = bih[        n] + bhh[        n];
    biasr1[g] = bih[192   + n] + bhh[192   + n];
    biasr2[g] = bih[2*192 + n] + bhh[2*192 + n];
  }

  // ---- stage adj/eps transposed: [t][b] ----
  if (tid < 128) {
    const int b = tid >> 5, q = tid & 31;
    const float4 va = reinterpret_cast<const float4*>(adj + (size_t)(b0+b)*128)[q];
    adjT[4*q+0][b]=va.x; adjT[4*q+1][b]=va.y; adjT[4*q+2][b]=va.z; adjT[4*q+3][b]=va.w;
    const float4 ve = reinterpret_cast<const float4*>(eps + (size_t)(b0+b)*128)[q];
    epsT[4*q+0][b]=ve.x; epsT[4*q+1][b]=ve.y; epsT[4*q+2][b]=ve.z; epsT[4*q+3][b]=ve.w;
  }
  const float bp0 = bp[0];
  __syncthreads();

  // ---- adjemb -> A_u (hbuf[0]), A_v (hbuf[1]) [one (b,jj) per thread]; pads ----
  {
    const int b = tid & 3, jj = tid >> 2;
    float s = ba[jj];
    const float* wr = Wa + jj*128;
    for (int t2 = 0; t2 < 128; ++t2) s += adjT[t2][b] * wr[t2];
    hbuf[0][b][jj] = f2bf(Wi[jj] * s);
    hbuf[1][b][jj] = f2bf(bi[jj] * s);
    hbuf[wv][lane >> 4][48 + (lane & 15)] = 0;   // zero pads, all (l,b,48..63)
  }
  __syncthreads();

  // ---- u,v via MFMA passes; keep only element kg (loop-invariant scalars) ----
  float u_k[4], vb_k[4];
  {
    const f32x4 z4 = {0.f,0.f,0.f,0.f};
    const unsigned short* rp = &hbuf[0][cr][0];
    u16x8 A0 = *reinterpret_cast<const u16x8*>(rp + 8*kg);
    u16x8 A1 = *reinterpret_cast<const u16x8*>(rp + 32 + 8*kg);
#pragma unroll
    for (int g = 0; g < 4; ++g) {
      f32x4 u = mfma16(A1, wfx[1][g], mfma16(A0, wfx[0][g], z4));
      u_k[g] = sel4(u, kg);
    }
    rp = &hbuf[1][cr][0];
    A0 = *reinterpret_cast<const u16x8*>(rp + 8*kg);
    A1 = *reinterpret_cast<const u16x8*>(rp + 32 + 8*kg);
#pragma unroll
    for (int g = 0; g < 4; ++g) {
      f32x4 v = mfma16(A1, wfx[1][g], mfma16(A0, wfx[0][g], z4));
      vb_k[g] = sel4(v, kg) + biasr0[g];
    }
  }
  __syncthreads();   // u/v reads done before h-init overwrites

  // ---- h/c init ----
  for (int cid = tid; cid < 576; cid += 192) {
    const int l = cid / 192, r2 = cid % 192, b = r2 & 3, jj = r2 >> 2;
    hbuf[l][b][jj] = f2bf(h0[l*48 + jj]);
  }
  float cv0 = c0[j], cv1 = c0[48 + j], cv2 = c0[2*48 + j];
  __syncthreads();

  // ---- pre-loop hoisted L0: gacc = vb_k-splat + Whh0 @ h0(init) ----
  f32x4 g0, g1, g2, g3;
  {
    const unsigned short* rp = &hbuf[0][cr][0];
    const u16x8 A0 = *reinterpret_cast<const u16x8*>(rp + 8*kg);
    const u16x8 A1 = *reinterpret_cast<const u16x8*>(rp + 32 + 8*kg);
    g0 = (f32x4){vb_k[0], vb_k[0], vb_k[0], vb_k[0]};
    g1 = (f32x4){vb_k[1], vb_k[1], vb_k[1], vb_k[1]};
    g2 = (f32x4){vb_k[2], vb_k[2], vb_k[2], vb_k[2]};
    g3 = (f32x4){vb_k[3], vb_k[3], vb_k[3], vb_k[3]};
    g0 = mfma16(A0, wf0[0][0], g0); g1 = mfma16(A0, wf0[0][1], g1);
    g2 = mfma16(A0, wf0[0][2], g2); g3 = mfma16(A0, wf0[0][3], g3);
    g0 = mfma16(A1, wf0[1][0], g0); g1 = mfma16(A1, wf0[1][1], g1);
    g2 = mfma16(A1, wf0[1][2], g2); g3 = mfma16(A1, wf0[1][3], g3);
  }

  const f32x4 bp4 = {bp0, bp0, bp0, bp0};
  f32x4 avR = {0.f,0.f,0.f,0.f}, evR = avR;   // prefetched adj/eps row for samp

  for (int t = 0; t < 128; ++t) {
    // ---- samp(t-1): MFMA mean from h2(t-1); scalar select for own batch ----
    float s_kg = 0.f;
    if (t) {
      const u16x8 mh0 = *reinterpret_cast<const u16x8*>(&hbuf[2][cr][8*kg]);
      const u16x8 mh1 = *reinterpret_cast<const u16x8*>(&hbuf[2][cr][32 + 8*kg]);
      f32x4 mz = {0.f,0.f,0.f,0.f};
      mz = mfma16(mh0, wpf[0], mz);
      mz = mfma16(mh1, wpf[1], mz);
      const f32x4 sampv = (mz + bp4 + evR) * avR;
      if (tid == 0)
        *reinterpret_cast<f32x4*>(&outb[t-1][0]) = sampv;
      s_kg = sel4(sampv, kg);
    }
    // ---- L0 cell: scalar gates = sel4(acc) + samp*u ----
    {
      const float gi = sel4(g0, kg) + s_kg*u_k[0];
      const float gf = sel4(g1, kg) + s_kg*u_k[1];
      const float gg = sel4(g2, kg) + s_kg*u_k[2];
      const float go = sel4(g3, kg) + s_kg*u_k[3];
      const float cn = sigm(gf)*cv0 + sigm(gi)*tanha(gg);
      cv0 = cn;
      hbuf[0][kg][j] = f2bf(sigm(go)*tanha(cn));
    }
    // prefetch L1 old-h half (h1(t-1); next written after B1 -> safe)
    u16x8 a11 = {0,0,0,0,0,0,0,0}, a12;
    if (kg >= 2) a11 = *reinterpret_cast<const u16x8*>(&hbuf[1][cr][8*kg - 16]);
    a12 = *reinterpret_cast<const u16x8*>(&hbuf[1][cr][16 + 8*kg]);
    __syncthreads();   // B1: h0(t) visible
    // ---- L1 ----
    {
      const unsigned short* rp = &hbuf[0][cr][0];
      const u16x8 a10 = *reinterpret_cast<const u16x8*>(rp + 8*kg);
      if (kg < 2) a11 = *reinterpret_cast<const u16x8*>(rp + 32 + 8*kg);
      f32x4 ac0 = {biasr1[0], biasr1[0], biasr1[0], biasr1[0]};
      f32x4 ac1 = {biasr1[1], biasr1[1], biasr1[1], biasr1[1]};
      f32x4 ac2 = {biasr1[2], biasr1[2], biasr1[2], biasr1[2]};
      f32x4 ac3 = {biasr1[3], biasr1[3], biasr1[3], biasr1[3]};
      MM4(a12, wf1[2]);   // prefetched operand first
      MM4(a10, wf1[0]);
      MM4(a11, wf1[1]);
      const float gi = sel4(ac0, kg), gf = sel4(ac1, kg);
      const float gg = sel4(ac2, kg), go = sel4(ac3, kg);
      const float cn = sigm(gf)*cv1 + sigm(gi)*tanha(gg);
      cv1 = cn;
      hbuf[1][kg][j] = f2bf(sigm(go)*tanha(cn));
    }
    // prefetch L2 old-h half (h2(t-1); next written after B2 -> safe)
    u16x8 a21 = {0,0,0,0,0,0,0,0}, a22;
    if (kg >= 2) a21 = *reinterpret_cast<const u16x8*>(&hbuf[2][cr][8*kg - 16]);
    a22 = *reinterpret_cast<const u16x8*>(&hbuf[2][cr][16 + 8*kg]);
    __syncthreads();   // B2: h1(t) visible
    // ---- L2 + prefetches + hoisted L0 for t+1 ----
    {
      const unsigned short* rp = &hbuf[1][cr][0];
      const u16x8 a20 = *reinterpret_cast<const u16x8*>(rp + 8*kg);
      if (kg < 2) a21 = *reinterpret_cast<const u16x8*>(rp + 32 + 8*kg);
      // prefetch next-step L0 A-frags (h0(t): written pre-B1, overwritten post-B3)
      const unsigned short* rp0 = &hbuf[0][cr][0];
      const u16x8 a00 = *reinterpret_cast<const u16x8*>(rp0 + 8*kg);
      const u16x8 a01 = *reinterpret_cast<const u16x8*>(rp0 + 32 + 8*kg);
      // prefetch adj/eps row t (read-only) for samp(t) at next loop top
      avR = *reinterpret_cast<const f32x4*>(&adjT[t][0]);
      evR = *reinterpret_cast<const f32x4*>(&epsT[t][0]);
      f32x4 ac0 = {biasr2[0], biasr2[0], biasr2[0], biasr2[0]};
      f32x4 ac1 = {biasr2[1], biasr2[1], biasr2[1], biasr2[1]};
      f32x4 ac2 = {biasr2[2], biasr2[2], biasr2[2], biasr2[2]};
      f32x4 ac3 = {biasr2[3], biasr2[3], biasr2[3], biasr2[3]};
      MM4(a22, wf2[2]);
      MM4(a20, wf2[0]);
      MM4(a21, wf2[1]);
      const float gi = sel4(ac0, kg), gf = sel4(ac1, kg);
      const float gg = sel4(ac2, kg), go = sel4(ac3, kg);
      const float cn = sigm(gf)*cv2 + sigm(gi)*tanha(gg);
      cv2 = cn;
      hbuf[2][kg][j] = f2bf(sigm(go)*tanha(cn));
      // hoisted L0 base gates for step t+1
      g0 = (f32x4){vb_k[0], vb_k[0], vb_k[0], vb_k[0]};
      g1 = (f32x4){vb_k[1], vb_k[1], vb_k[1], vb_k[1]};
      g2 = (f32x4){vb_k[2], vb_k[2], vb_k[2], vb_k[2]};
      g3 = (f32x4){vb_k[3], vb_k[3], vb_k[3], vb_k[3]};
      g0 = mfma16(a00, wf0[0][0], g0); g1 = mfma16(a00, wf0[0][1], g1);
      g2 = mfma16(a00, wf0[0][2], g2); g3 = mfma16(a00, wf0[0][3], g3);
      g0 = mfma16(a01, wf0[1][0], g0); g1 = mfma16(a01, wf0[1][1], g1);
      g2 = mfma16(a01, wf0[1][2], g2); g3 = mfma16(a01, wf0[1][3], g3);
    }
    __syncthreads();   // B3: h2(t) + all h-writes settled
  }
  // ---- epilogue: samp(127) ----
  {
    const u16x8 mh0 = *reinterpret_cast<const u16x8*>(&hbuf[2][cr][8*kg]);
    const u16x8 mh1 = *reinterpret_cast<const u16x8*>(&hbuf[2][cr][32 + 8*kg]);
    f32x4 mz = {0.f,0.f,0.f,0.f};
    mz = mfma16(mh0, wpf[0], mz);
    mz = mfma16(mh1, wpf[1], mz);
    const f32x4 sv = (mz + bp4 + evR) * avR;   // avR/evR hold row 127
    if (tid == 0)
      *reinterpret_cast<f32x4*>(&outb[127][0]) = sv;
  }
  __syncthreads();
  // ---- final coalesced store ----
  for (int i = tid; i < 512; i += 192) {
    const int b = i >> 7, tt = i & 127;
    out[(size_t)(b0 + b)*128 + tt] = outb[tt][b];
  }
}

extern "C" void kernel_launch(void* const* d_in, const int* in_sizes, int n_in,
                              void* d_out, int out_size, void* d_ws, size_t ws_size,
                              hipStream_t stream) {
  const float* adj = (const float*)d_in[0];
  const float* eps = (const float*)d_in[1];
  const float* Wi  = (const float*)d_in[2];
  const float* bi  = (const float*)d_in[3];
  const float* Wa  = (const float*)d_in[4];
  const float* ba  = (const float*)d_in[5];
  const float* Wp  = (const float*)d_in[6];
  const float* bp  = (const float*)d_in[7];
  const float* Wih = (const float*)d_in[8];
  const float* Whh = (const float*)d_in[9];
  const float* bih = (const float*)d_in[10];
  const float* bhh = (const float*)d_in[11];
  const float* h0  = (const float*)d_in[12];
  const float* c0  = (const float*)d_in[13];

  lstm_fused<<<dim3(2048/4), dim3(192), 0, stream>>>(
      adj, eps, Wi, bi, Wa, ba, Wp, bp, Wih, Whh, bih, bhh, h0, c0, (float*)d_out);
}

// Round 11
// 150.682 us; speedup vs baseline: 1.7154x; 1.7154x over previous
//
#include <hip/hip_runtime.h>
#include <hip/hip_bf16.h>

// B=2048, T=128, H=48, L=3. Gates G=192.
// WG = 3 waves (192 thr) x 8 batches; 256 WGs = 1/CU (one pass).
// LESSON (R9/R10): gfx950 wave64 VGPR pool = 256/SIMD -> 2 waves/SIMD needs
// VGPR<=128, impossible with register-resident weights (136 VGPR). So run
// 1 WG/CU, grid 256, and minimize the serial chain.
// Chain: 3 barriers/step; samp via MFMA-mean (Wp replicated cols); L0 rank-1
// samp fold (scalar); hoisted L0 MFMAs; rational-form LSTM cell (7 trans/cell).
//
// Mapping (validated R1-R8): A-frag lane(c,kg) = A[m=c][k=8kg..+7] per
// 32-wide ktile; B-frag = W[n][k0..+7], n = 48g+16wv+c; D elem r of lane
// (c,kg) = D[m=4kg+r][n=c], batch = m&7 = bq+r, bq=4*(kg&1). Lane owns cells
// (j=16wv+c, b=bbase,bbase+1), bbase=bq+2*(kg>>1); acc elems {0,1} if kg<2
// else {2,3}.

using bf16x8 = __attribute__((ext_vector_type(8))) __bf16;
using u16x8  = __attribute__((ext_vector_type(8))) unsigned short;
using f32x4  = __attribute__((ext_vector_type(4))) float;

__device__ __forceinline__ float fexp2(float x){ return __builtin_amdgcn_exp2f(x); }
__device__ __forceinline__ float frcp (float x){ return __builtin_amdgcn_rcpf(x); }

__device__ __forceinline__ unsigned short f2bf(float x){
  unsigned u = __float_as_uint(x);
  return (unsigned short)((u + 0x7FFFu + ((u>>16)&1u)) >> 16);  // RNE
}

__device__ __forceinline__ f32x4 mfma16(u16x8 a, u16x8 b, f32x4 c){
  return __builtin_amdgcn_mfma_f32_16x16x32_bf16(
      __builtin_bit_cast(bf16x8, a), __builtin_bit_cast(bf16x8, b), c, 0, 0, 0);
}

__device__ __forceinline__ float selA(const f32x4& a, bool lo){ return lo ? a[0] : a[2]; }
__device__ __forceinline__ float selB(const f32x4& a, bool lo){ return lo ? a[1] : a[3]; }

// Rational-form LSTM cell: cn = sig(gf)*cv + sig(gi)*tanh(gg); h = sig(go)*tanh(cn).
// Shared denominators: 5 exp + 2 rcp (vs 5 exp + 5 rcp naive). Exact algebra.
__device__ __forceinline__ float cell_h(float gi, float gf, float gg, float go, float& cv){
  const float A = fexp2(-1.44269504f*gf);      // e^-gf
  const float B = fexp2(-1.44269504f*gi);      // e^-gi
  const float G = fexp2(-2.88539008f*gg);      // e^-2gg
  const float pBG = (1.f+B)*(1.f+G);
  const float nc  = cv*pBG + (1.f+A)*(1.f-G);
  const float cn  = nc * frcp((1.f+A)*pBG);
  cv = cn;
  const float O = fexp2(-1.44269504f*go);      // e^-go
  const float C = fexp2(-2.88539008f*cn);      // e^-2cn
  return (1.f-C) * frcp((1.f+O)*(1.f+C));
}

#define MM4(A, WK) \
  ac0 = mfma16(A, WK[0], ac0); ac1 = mfma16(A, WK[1], ac1); \
  ac2 = mfma16(A, WK[2], ac2); ac3 = mfma16(A, WK[3], ac3);

__global__ __launch_bounds__(192, 1) void lstm_fused(
    const float* __restrict__ adj, const float* __restrict__ eps,
    const float* __restrict__ Wi,  const float* __restrict__ bi,
    const float* __restrict__ Wa,  const float* __restrict__ ba,
    const float* __restrict__ Wp,  const float* __restrict__ bp,
    const float* __restrict__ Wih, const float* __restrict__ Whh,
    const float* __restrict__ bih, const float* __restrict__ bhh,
    const float* __restrict__ h0,  const float* __restrict__ c0,
    float* __restrict__ out)
{
  const int tid   = threadIdx.x;
  const int wv    = tid >> 6;          // 0..2
  const int lane  = tid & 63;
  const int c     = lane & 15;
  const int kg    = lane >> 4;         // 0..3
  const int j     = 16*wv + c;         // owned hidden index
  const int b0    = blockIdx.x * 8;    // 8 batches per WG
  const int bq    = 4*(kg & 1);        // acc elem r -> batch bq+r
  const int bbase = bq + 2*(kg >> 1);  // owned batch pair
  const bool lo   = (kg < 2);          // owned acc elems {0,1} vs {2,3}
  const int cr    = c & 7;             // A-row batch for frag reads

  __shared__ __align__(16) unsigned short hbuf[3][8][104]; // h per layer; [48..63]=0 pad
  __shared__ __align__(16) float adjT[128][8];
  __shared__ __align__(16) float epsT[128][8];
  __shared__ __align__(16) float outb[128][8];             // samples, stored at end

  // ---- weight fragments -> registers ----
  u16x8 wf1[3][4], wf2[3][4];  // layers 1,2: [Wih|Whh], K=96
  u16x8 wf0[2][4], wfx[2][4];  // layer 0: Whh (K=48 pad 64); Wih for u/v passes
  u16x8 wpf[2];                // Wp replicated to all 16 columns (mean-MFMA)
  float biasr0[4], biasr1[4], biasr2[4];
#pragma unroll
  for (int kk = 0; kk < 3; ++kk) {
    const int k0 = 32*kk + 8*kg;
#pragma unroll
    for (int g = 0; g < 4; ++g) {
      const int n = 48*g + j;
#pragma unroll
      for (int l = 1; l < 3; ++l) {
        const float* src = (k0 < 48) ? (Wih + ((l*192 + n)*48 + k0))
                                     : (Whh + ((l*192 + n)*48 + (k0 - 48)));
        float4 p0 = *reinterpret_cast<const float4*>(src);
        float4 p1 = *reinterpret_cast<const float4*>(src + 4);
        u16x8 f;
        f[0]=f2bf(p0.x); f[1]=f2bf(p0.y); f[2]=f2bf(p0.z); f[3]=f2bf(p0.w);
        f[4]=f2bf(p1.x); f[5]=f2bf(p1.y); f[6]=f2bf(p1.z); f[7]=f2bf(p1.w);
        if (l == 1) wf1[kk][g] = f; else wf2[kk][g] = f;
      }
    }
  }
#pragma unroll
  for (int kk = 0; kk < 2; ++kk) {
    const int k0 = 32*kk + 8*kg;
#pragma unroll
    for (int g = 0; g < 4; ++g) {
      const int n = 48*g + j;
      u16x8 fh = {0,0,0,0,0,0,0,0}, fx = fh;
      if (k0 < 48) {
        const float* sh = Whh + (n*48 + k0);      // layer 0
        const float* sx = Wih + (n*48 + k0);
        float4 p0 = *reinterpret_cast<const float4*>(sh);
        float4 p1 = *reinterpret_cast<const float4*>(sh + 4);
        fh[0]=f2bf(p0.x); fh[1]=f2bf(p0.y); fh[2]=f2bf(p0.z); fh[3]=f2bf(p0.w);
        fh[4]=f2bf(p1.x); fh[5]=f2bf(p1.y); fh[6]=f2bf(p1.z); fh[7]=f2bf(p1.w);
        p0 = *reinterpret_cast<const float4*>(sx);
        p1 = *reinterpret_cast<const float4*>(sx + 4);
        fx[0]=f2bf(p0.x); fx[1]=f2bf(p0.y); fx[2]=f2bf(p0.z); fx[3]=f2bf(p0.w);
        fx[4]=f2bf(p1.x); fx[5]=f2bf(p1.y); fx[6]=f2bf(p1.z); fx[7]=f2bf(p1.w);
      }
      wf0[kk][g] = fh; wfx[kk][g] = fx;
    }
    u16x8 fp = {0,0,0,0,0,0,0,0};
#pragma unroll
    for (int e = 0; e < 8; ++e) {
      const int k = k0 + e;
      if (k < 48) fp[e] = f2bf(Wp[k]);
    }
    wpf[kk] = fp;   // same for every column c -> every lane's acc = mean
  }
#pragma unroll
  for (int g = 0; g < 4; ++g) {
    const int n = 48*g + j;
    biasr0[g] = bih[        n] + bhh[        n];
    biasr1[g] = bih[192   + n] + bhh[192   + n];
    biasr2[g] = bih[2*192 + n] + bhh[2*192 + n];
  }

  // ---- stage adj/eps transposed: [t][b] ----
  for (int i = tid; i < 256; i += 192) {
    const int b = i >> 5, q = i & 31;
    const float4 va = reinterpret_cast<const float4*>(adj + (size_t)(b0+b)*128)[q];
    adjT[4*q+0][b]=va.x; adjT[4*q+1][b]=va.y; adjT[4*q+2][b]=va.z; adjT[4*q+3][b]=va.w;
    const float4 ve = reinterpret_cast<const float4*>(eps + (size_t)(b0+b)*128)[q];
    epsT[4*q+0][b]=ve.x; epsT[4*q+1][b]=ve.y; epsT[4*q+2][b]=ve.z; epsT[4*q+3][b]=ve.w;
  }
  const float bp0 = bp[0];
  __syncthreads();

  // ---- adjemb -> A_u (hbuf[0]), A_v (hbuf[1]); zero pads ----
  for (int cid = tid; cid < 384; cid += 192) {
    const int b = cid & 7, jj = cid >> 3;
    float s = ba[jj];
    const float* wr = Wa + jj*128;
    for (int t2 = 0; t2 < 128; ++t2) s += adjT[t2][b] * wr[t2];
    hbuf[0][b][jj] = f2bf(Wi[jj] * s);
    hbuf[1][b][jj] = f2bf(bi[jj] * s);
  }
  for (int cid = tid; cid < 384; cid += 192) {   // pads j 48..63, all 3 layers
    const int l = cid / 128, r2 = cid % 128, b = r2 >> 4, jj = 48 + (r2 & 15);
    hbuf[l][b][jj] = 0;
  }
  __syncthreads();

  // ---- u,v via MFMA passes; keep only this lane's two cell elems (scalars) ----
  float uA[4], uB[4], vbA[4], vbB[4];
  {
    const f32x4 z4 = {0.f,0.f,0.f,0.f};
    const unsigned short* rp = &hbuf[0][cr][0];
    u16x8 A0 = *reinterpret_cast<const u16x8*>(rp + 8*kg);
    u16x8 A1 = *reinterpret_cast<const u16x8*>(rp + 32 + 8*kg);
#pragma unroll
    for (int g = 0; g < 4; ++g) {
      f32x4 u = mfma16(A1, wfx[1][g], mfma16(A0, wfx[0][g], z4));
      uA[g] = selA(u, lo); uB[g] = selB(u, lo);
    }
    rp = &hbuf[1][cr][0];
    A0 = *reinterpret_cast<const u16x8*>(rp + 8*kg);
    A1 = *reinterpret_cast<const u16x8*>(rp + 32 + 8*kg);
#pragma unroll
    for (int g = 0; g < 4; ++g) {
      f32x4 v = mfma16(A1, wfx[1][g], mfma16(A0, wfx[0][g], z4));
      vbA[g] = selA(v, lo) + biasr0[g];
      vbB[g] = selB(v, lo) + biasr0[g];
    }
  }
  __syncthreads();   // u/v reads done before h-init overwrites

  // ---- h/c init ----
  for (int cid = tid; cid < 1152; cid += 192) {
    const int l = cid / 384, r2 = cid % 384, b = r2 & 7, jj = r2 >> 3;
    hbuf[l][b][jj] = f2bf(h0[l*48 + jj]);
  }
  float cc0A, cc0B, cc1A, cc1B, cc2A, cc2B;
  cc0A = cc0B = c0[       j];
  cc1A = cc1B = c0[48   + j];
  cc2A = cc2B = c0[2*48 + j];
  __syncthreads();

  // ---- pre-loop: gacc = vb(2-pt init) + Whh0 @ h0(init) ----
  // unused acc elems carry garbage-tolerant values: only elems (lo?{0,1}:{2,3}) read.
  f32x4 g0, g1, g2, g3;
  {
    const unsigned short* rp = &hbuf[0][cr][0];
    const u16x8 A0 = *reinterpret_cast<const u16x8*>(rp + 8*kg);
    const u16x8 A1 = *reinterpret_cast<const u16x8*>(rp + 32 + 8*kg);
    g0 = (f32x4){vbA[0], vbB[0], vbA[0], vbB[0]};
    g1 = (f32x4){vbA[1], vbB[1], vbA[1], vbB[1]};
    g2 = (f32x4){vbA[2], vbB[2], vbA[2], vbB[2]};
    g3 = (f32x4){vbA[3], vbB[3], vbA[3], vbB[3]};
    g0 = mfma16(A0, wf0[0][0], g0); g1 = mfma16(A0, wf0[0][1], g1);
    g2 = mfma16(A0, wf0[0][2], g2); g3 = mfma16(A0, wf0[0][3], g3);
    g0 = mfma16(A1, wf0[1][0], g0); g1 = mfma16(A1, wf0[1][1], g1);
    g2 = mfma16(A1, wf0[1][2], g2); g3 = mfma16(A1, wf0[1][3], g3);
  }

  const f32x4 bp4 = {bp0, bp0, bp0, bp0};
  f32x4 avR = {0.f,0.f,0.f,0.f}, evR = avR;   // prefetched adj/eps row for samp

  for (int t = 0; t < 128; ++t) {
    // ---- samp(t-1): MFMA mean from h2(t-1); independent accs, scalar select ----
    float sA = 0.f, sB = 0.f;
    if (t) {
      const u16x8 mh0 = *reinterpret_cast<const u16x8*>(&hbuf[2][cr][8*kg]);
      const u16x8 mh1 = *reinterpret_cast<const u16x8*>(&hbuf[2][cr][32 + 8*kg]);
      f32x4 mz0 = {0.f,0.f,0.f,0.f}, mz1 = mz0;
      mz0 = mfma16(mh0, wpf[0], mz0);
      mz1 = mfma16(mh1, wpf[1], mz1);
      const f32x4 sampv = (mz0 + mz1 + bp4 + evR) * avR;
      if (tid == 0 || tid == 16)
        *reinterpret_cast<f32x4*>(&outb[t-1][bq]) = sampv;
      sA = selA(sampv, lo); sB = selB(sampv, lo);
    }
    // prefetch L1 old-h half early (latency hides under L0 trans; safe pre-B1)
    u16x8 a11 = {0,0,0,0,0,0,0,0}, a12;
    if (kg >= 2) a11 = *reinterpret_cast<const u16x8*>(&hbuf[1][cr][8*kg - 16]);
    a12 = *reinterpret_cast<const u16x8*>(&hbuf[1][cr][16 + 8*kg]);
    // ---- L0 cell: scalar gates = sel(acc) + samp*u ----
    {
      const float hA = cell_h(selA(g0,lo)+sA*uA[0], selA(g1,lo)+sA*uA[1],
                              selA(g2,lo)+sA*uA[2], selA(g3,lo)+sA*uA[3], cc0A);
      const float hB = cell_h(selB(g0,lo)+sB*uB[0], selB(g1,lo)+sB*uB[1],
                              selB(g2,lo)+sB*uB[2], selB(g3,lo)+sB*uB[3], cc0B);
      unsigned pk;
      asm("v_cvt_pk_bf16_f32 %0, %1, %2" : "=v"(pk) : "v"(hA), "v"(hB));
      hbuf[0][bbase    ][j] = (unsigned short)pk;
      hbuf[0][bbase + 1][j] = (unsigned short)(pk >> 16);
    }
    // hoisted L1 old-K MFMAs (a12 = h1(t-1), all lanes valid) before the barrier
    f32x4 ac0 = {biasr1[0], biasr1[0], biasr1[0], biasr1[0]};
    f32x4 ac1 = {biasr1[1], biasr1[1], biasr1[1], biasr1[1]};
    f32x4 ac2 = {biasr1[2], biasr1[2], biasr1[2], biasr1[2]};
    f32x4 ac3 = {biasr1[3], biasr1[3], biasr1[3], biasr1[3]};
    MM4(a12, wf1[2]);
    __syncthreads();   // B1: h0(t) visible
    // ---- L1 ----
    {
      const unsigned short* rp = &hbuf[0][cr][0];
      const u16x8 a10 = *reinterpret_cast<const u16x8*>(rp + 8*kg);
      if (kg < 2) a11 = *reinterpret_cast<const u16x8*>(rp + 32 + 8*kg);
      MM4(a10, wf1[0]);
      MM4(a11, wf1[1]);
    }
    // prefetch L2 old-h half early (latency hides under L1 trans; safe pre-B2)
    u16x8 a21 = {0,0,0,0,0,0,0,0}, a22;
    if (kg >= 2) a21 = *reinterpret_cast<const u16x8*>(&hbuf[2][cr][8*kg - 16]);
    a22 = *reinterpret_cast<const u16x8*>(&hbuf[2][cr][16 + 8*kg]);
    {
      const float hA = cell_h(selA(ac0,lo), selA(ac1,lo), selA(ac2,lo), selA(ac3,lo), cc1A);
      const float hB = cell_h(selB(ac0,lo), selB(ac1,lo), selB(ac2,lo), selB(ac3,lo), cc1B);
      unsigned pk;
      asm("v_cvt_pk_bf16_f32 %0, %1, %2" : "=v"(pk) : "v"(hA), "v"(hB));
      hbuf[1][bbase    ][j] = (unsigned short)pk;
      hbuf[1][bbase + 1][j] = (unsigned short)(pk >> 16);
    }
    // hoisted L2 old-K MFMAs (a22 = h2(t-1)) before the barrier
    ac0 = (f32x4){biasr2[0], biasr2[0], biasr2[0], biasr2[0]};
    ac1 = (f32x4){biasr2[1], biasr2[1], biasr2[1], biasr2[1]};
    ac2 = (f32x4){biasr2[2], biasr2[2], biasr2[2], biasr2[2]};
    ac3 = (f32x4){biasr2[3], biasr2[3], biasr2[3], biasr2[3]};
    MM4(a22, wf2[2]);
    __syncthreads();   // B2: h1(t) visible
    // ---- L2 + prefetches + hoisted L0 for t+1 ----
    {
      const unsigned short* rp = &hbuf[1][cr][0];
      const u16x8 a20 = *reinterpret_cast<const u16x8*>(rp + 8*kg);
      if (kg < 2) a21 = *reinterpret_cast<const u16x8*>(rp + 32 + 8*kg);
      MM4(a20, wf2[0]);
      MM4(a21, wf2[1]);
      // prefetch next-step L0 A-frags (h0(t): written pre-B1, next write post-B3)
      const unsigned short* rp0 = &hbuf[0][cr][0];
      const u16x8 a00 = *reinterpret_cast<const u16x8*>(rp0 + 8*kg);
      const u16x8 a01 = *reinterpret_cast<const u16x8*>(rp0 + 32 + 8*kg);
      // prefetch adj/eps row t (read-only) for samp(t) at next loop top
      avR = *reinterpret_cast<const f32x4*>(&adjT[t][bq]);
      evR = *reinterpret_cast<const f32x4*>(&epsT[t][bq]);
      const float hA = cell_h(selA(ac0,lo), selA(ac1,lo), selA(ac2,lo), selA(ac3,lo), cc2A);
      const float hB = cell_h(selB(ac0,lo), selB(ac1,lo), selB(ac2,lo), selB(ac3,lo), cc2B);
      unsigned pk;
      asm("v_cvt_pk_bf16_f32 %0, %1, %2" : "=v"(pk) : "v"(hA), "v"(hB));
      hbuf[2][bbase    ][j] = (unsigned short)pk;
      hbuf[2][bbase + 1][j] = (unsigned short)(pk >> 16);
      // hoisted L0 base gates for step t+1
      g0 = (f32x4){vbA[0], vbB[0], vbA[0], vbB[0]};
      g1 = (f32x4){vbA[1], vbB[1], vbA[1], vbB[1]};
      g2 = (f32x4){vbA[2], vbB[2], vbA[2], vbB[2]};
      g3 = (f32x4){vbA[3], vbB[3], vbA[3], vbB[3]};
      g0 = mfma16(a00, wf0[0][0], g0); g1 = mfma16(a00, wf0[0][1], g1);
      g2 = mfma16(a00, wf0[0][2], g2); g3 = mfma16(a00, wf0[0][3], g3);
      g0 = mfma16(a01, wf0[1][0], g0); g1 = mfma16(a01, wf0[1][1], g1);
      g2 = mfma16(a01, wf0[1][2], g2); g3 = mfma16(a01, wf0[1][3], g3);
    }
    __syncthreads();   // B3: h2(t) + all h-writes settled
  }
  // ---- epilogue: samp(127) ----
  {
    const u16x8 mh0 = *reinterpret_cast<const u16x8*>(&hbuf[2][cr][8*kg]);
    const u16x8 mh1 = *reinterpret_cast<const u16x8*>(&hbuf[2][cr][32 + 8*kg]);
    f32x4 mz0 = {0.f,0.f,0.f,0.f}, mz1 = mz0;
    mz0 = mfma16(mh0, wpf[0], mz0);
    mz1 = mfma16(mh1, wpf[1], mz1);
    const f32x4 sv = (mz0 + mz1 + bp4 + evR) * avR;   // avR/evR hold row 127
    if (tid == 0 || tid == 16)
      *reinterpret_cast<f32x4*>(&outb[127][bq]) = sv;
  }
  __syncthreads();
  // ---- final coalesced store of all samples ----
  for (int i = tid; i < 1024; i += 192) {
    const int b = i >> 7, tt = i & 127;
    out[(size_t)(b0 + b)*128 + tt] = outb[tt][b];
  }
}

extern "C" void kernel_launch(void* const* d_in, const int* in_sizes, int n_in,
                              void* d_out, int out_size, void* d_ws, size_t ws_size,
                              hipStream_t stream) {
  const float* adj = (const float*)d_in[0];
  const float* eps = (const float*)d_in[1];
  const float* Wi  = (const float*)d_in[2];
  const float* bi  = (const float*)d_in[3];
  const float* Wa  = (const float*)d_in[4];
  const float* ba  = (const float*)d_in[5];
  const float* Wp  = (const float*)d_in[6];
  const float* bp  = (const float*)d_in[7];
  const float* Wih = (const float*)d_in[8];
  const float* Whh = (const float*)d_in[9];
  const float* bih = (const float*)d_in[10];
  const float* bhh = (const float*)d_in[11];
  const float* h0  = (const float*)d_in[12];
  const float* c0  = (const float*)d_in[13];

  lstm_fused<<<dim3(2048/8), dim3(192), 0, stream>>>(
      adj, eps, Wi, bi, Wa, ba, Wp, bp, Wih, Whh, bih, bhh, h0, c0, (float*)d_out);
}